// Round 16
// baseline (483.849 us; speedup 1.0000x reference)
//
#include <hip/hip_runtime.h>
#include <hip/hip_bf16.h>

namespace {
constexpr int Bn = 512;
constexpr int Ln = 1024;
constexpr int Vn = 64;
constexpr int En = 128;
constexpr int Kc = Vn + En;              // 192
constexpr size_t WALLB_BYTES = (size_t)En * Kc * 2;  // 49,152
constexpr size_t BC_BYTES    = En * 4;               // 512
constexpr size_t WOUTP_BYTES = (size_t)Vn * En * 2;  // 16,384
constexpr size_t SMALL_WS = WALLB_BYTES + BC_BYTES + WOUTP_BYTES;  // ~66 KB
}

typedef __attribute__((ext_vector_type(8))) short bf16x8;
typedef __attribute__((ext_vector_type(4))) float f32x4;

__device__ __forceinline__ unsigned f2b(float f) {
  unsigned u = __float_as_uint(f);
  u += 0x7fffu + ((u >> 16) & 1u);
  return u >> 16;
}
__device__ __forceinline__ float b2f(unsigned short b) {
  return __uint_as_float(((unsigned)b) << 16);
}
__device__ __forceinline__ bf16x8 pack8(const float* v) {
  bf16x8 r;
#pragma unroll
  for (int i = 0; i < 8; ++i) r[i] = (short)f2b(v[i]);
  return r;
}

// column permutation for the h cycle (16x16x32, 4-wave):
// k-tile tau, frag elem e at k-group lg:  kk = 32*tau + 8*lg + e
// -> h col m(kk) = 32*tau + 16*(e>>2) + 4*lg + (e&3)
__device__ __forceinline__ int cm4(int kk) {
  return 32 * (kk >> 5) + 16 * ((kk >> 2) & 1) + 4 * ((kk >> 3) & 3) + (kk & 3);
}

#define MFMA __builtin_amdgcn_mfma_f32_16x16x32_bf16

// ---------------- merged setup: wall2 + bc (blocks 0..127), woutp (128..191) ----
__global__ __launch_bounds__(192) void rnn_setup_all(
    const float* __restrict__ W_in, const float* __restrict__ b_in,
    const float* __restrict__ W_h, const float* __restrict__ b_h,
    const float* __restrict__ W_out, unsigned short* __restrict__ wall2,
    float* __restrict__ bc, unsigned short* __restrict__ woutp) {
  const int tid = threadIdx.x;
  if (blockIdx.x < 128) {
    const int j = blockIdx.x;
    const int k = tid;  // 0..191
    const float* whr = W_h + j * (2 * En);
    float s;
    if (k < Vn) {
      s = 0.f;
#pragma unroll 8
      for (int e = 0; e < En; ++e) s = fmaf(W_in[e * Vn + k], whr[e], s);
    } else {
      s = whr[En + cm4(k - Vn)];
    }
    wall2[j * Kc + k] = (unsigned short)f2b(s);
    if (k == 0) {
      float b = b_h[j];
      for (int e = 0; e < En; ++e) b = fmaf(b_in[e], whr[e], b);
      bc[j] = b;
    }
  } else {
    const int v = blockIdx.x - 128;  // 0..63
    if (tid < En)
      woutp[v * En + tid] = (unsigned short)f2b(W_out[(size_t)v * En + cm4(tid)]);
  }
}

// ---------------- main kernel: r13 structure, fp32 seq loaded directly ----------
// 4 waves (1/SIMD). Wave w owns n-tiles {2w,2w+1} = h cols [32w,32w+32) = z
// k-tile w; under cm4 its packed relu output IS its own 16B B-frag (zown,
// register-resident). 3 foreign tiles via lane-linear conflict-free LDS
// (tile = 1024B, lane l at byte l*16). Per step: 12 MFMA (4 seq + 8 z),
// 3 ds_read_b128 + 1 ds_write_b128, 1 drain+barrier. seq is loaded fp32
// (4x dwordx4, 3-step prefetch) and packed in-loop with 8 v_cvt_pk — the
// step has >=140cyc issue slack at its ~570cyc latency floor, so this is free
// and eliminates the seq_cvt prepass entirely.
__global__ __launch_bounds__(256, 1) void rnn_quad_f32(
    const float* __restrict__ seq, const unsigned short* __restrict__ wall2,
    const float* __restrict__ bc, const unsigned short* __restrict__ woutp,
    const float* __restrict__ b_out, float* __restrict__ out) {
  __shared__ __align__(16) unsigned char zlds[2][4][1024];  // [buf][tile][lane16B]

  const int tid = threadIdx.x;
  const int w   = tid >> 6;        // wave 0..3 = owned k-tile
  const int l   = tid & 63;
  const int l15 = l & 15;          // batch col / A row
  const int lg  = l >> 4;          // k-group / C row-group
  const int r0  = blockIdx.x * 16;

  // weights for n-tiles 2w (Aw[0]) and 2w+1 (Aw[1]); [kt]: 0,1=seq, 2+p=z tile (w+p)&3
  bf16x8 Aw[2][6];
#pragma unroll
  for (int nn = 0; nn < 2; ++nn) {
    const unsigned short* row = wall2 + (size_t)(16 * (2 * w + nn) + l15) * Kc + lg * 8;
    Aw[nn][0] = *(const bf16x8*)(row);
    Aw[nn][1] = *(const bf16x8*)(row + 32);
#pragma unroll
    for (int p = 0; p < 4; ++p)
      Aw[nn][2 + p] = *(const bf16x8*)(row + Vn + 32 * ((w + p) & 3));
  }
  const f32x4 bcv0 = *(const f32x4*)(bc + 32 * w + 4 * lg);
  const f32x4 bcv1 = *(const f32x4*)(bc + 32 * w + 16 + 4 * lg);

  const int ro  = l * 16;  // lane slot within a tile (stride-1, conflict-free)
  const unsigned char* rA1 = &zlds[0][(w + 1) & 3][ro];
  const unsigned char* rA2 = &zlds[0][(w + 2) & 3][ro];
  const unsigned char* rA3 = &zlds[0][(w + 3) & 3][ro];
  const unsigned char* rB1 = &zlds[1][(w + 1) & 3][ro];
  const unsigned char* rB2 = &zlds[1][(w + 2) & 3][ro];
  const unsigned char* rB3 = &zlds[1][(w + 3) & 3][ro];
  unsigned char* wA = &zlds[0][w][ro];
  unsigned char* wB = &zlds[1][w][ro];

  // h(0) = 0
  for (int i = tid; i < 2048; i += 256) ((unsigned int*)zlds)[i] = 0u;
  bf16x8 zown;
#pragma unroll
  for (int i = 0; i < 8; ++i) zown[i] = 0;

  // fp32 seq source: lane (l15,lg) needs elems [8lg,8lg+8) and [32+8lg,+8)
  const float* sqf = seq + ((size_t)(r0 + l15) * Ln) * Vn + lg * 8;
  f32x4 sbuf[4][4];  // [buf][0,1]=frag0, [2,3]=frag1

#define SEQ_PF(BI, T)                                                 \
  { const int tp = ((T) < Ln) ? (T) : (Ln - 1);                       \
    const float* s4 = sqf + (size_t)tp * Vn;                          \
    sbuf[BI][0] = *(const f32x4*)(s4);                                \
    sbuf[BI][1] = *(const f32x4*)(s4 + 4);                            \
    sbuf[BI][2] = *(const f32x4*)(s4 + 32);                           \
    sbuf[BI][3] = *(const f32x4*)(s4 + 36); }

  SEQ_PF(0, 0)
  SEQ_PF(1, 1)
  SEQ_PF(2, 2)
  __syncthreads();

  // step: read 3 foreign tiles of z(t) from buf[t&1]; own tile = zown (reg).
  // pack seq (slack); 12 MFMAs; pack -> zown; write; drain; barrier.
#define PHASE(P, R1, R2, R3, WR)                                              \
  {                                                                           \
    const bf16x8 zf1 = *(const bf16x8*)(R1);                                  \
    const bf16x8 zf2 = *(const bf16x8*)(R2);                                  \
    const bf16x8 zf3 = *(const bf16x8*)(R3);                                  \
    SEQ_PF(((P) + 3) & 3, t + (P) + 3);                                       \
    unsigned sa0, sa1, sa2, sa3, sb0, sb1, sb2, sb3;                          \
    asm("v_cvt_pk_bf16_f32 %0, %1, %2" : "=v"(sa0)                            \
        : "v"(sbuf[(P)][0][0]), "v"(sbuf[(P)][0][1]));                        \
    asm("v_cvt_pk_bf16_f32 %0, %1, %2" : "=v"(sa1)                            \
        : "v"(sbuf[(P)][0][2]), "v"(sbuf[(P)][0][3]));                        \
    asm("v_cvt_pk_bf16_f32 %0, %1, %2" : "=v"(sa2)                            \
        : "v"(sbuf[(P)][1][0]), "v"(sbuf[(P)][1][1]));                        \
    asm("v_cvt_pk_bf16_f32 %0, %1, %2" : "=v"(sa3)                            \
        : "v"(sbuf[(P)][1][2]), "v"(sbuf[(P)][1][3]));                        \
    asm("v_cvt_pk_bf16_f32 %0, %1, %2" : "=v"(sb0)                            \
        : "v"(sbuf[(P)][2][0]), "v"(sbuf[(P)][2][1]));                        \
    asm("v_cvt_pk_bf16_f32 %0, %1, %2" : "=v"(sb1)                            \
        : "v"(sbuf[(P)][2][2]), "v"(sbuf[(P)][2][3]));                        \
    asm("v_cvt_pk_bf16_f32 %0, %1, %2" : "=v"(sb2)                            \
        : "v"(sbuf[(P)][3][0]), "v"(sbuf[(P)][3][1]));                        \
    asm("v_cvt_pk_bf16_f32 %0, %1, %2" : "=v"(sb3)                            \
        : "v"(sbuf[(P)][3][2]), "v"(sbuf[(P)][3][3]));                        \
    union { unsigned u[4]; bf16x8 v; } S0_, S1_;                              \
    S0_.u[0] = sa0; S0_.u[1] = sa1; S0_.u[2] = sa2; S0_.u[3] = sa3;           \
    S1_.u[0] = sb0; S1_.u[1] = sb1; S1_.u[2] = sb2; S1_.u[3] = sb3;           \
    const bf16x8 s0 = S0_.v, s1 = S1_.v;                                      \
    f32x4 p0 = MFMA(Aw[0][0], s0, bcv0, 0, 0, 0);                             \
    f32x4 p1 = MFMA(Aw[1][0], s0, bcv1, 0, 0, 0);                             \
    f32x4 q0 = {0.f, 0.f, 0.f, 0.f}, q1 = {0.f, 0.f, 0.f, 0.f};               \
    q0 = MFMA(Aw[0][1], s1, q0, 0, 0, 0);                                     \
    q1 = MFMA(Aw[1][1], s1, q1, 0, 0, 0);                                     \
    p0 = MFMA(Aw[0][2], zown, p0, 0, 0, 0);                                   \
    p1 = MFMA(Aw[1][2], zown, p1, 0, 0, 0);                                   \
    q0 = MFMA(Aw[0][3], zf1, q0, 0, 0, 0);                                    \
    q1 = MFMA(Aw[1][3], zf1, q1, 0, 0, 0);                                    \
    p0 = MFMA(Aw[0][4], zf2, p0, 0, 0, 0);                                    \
    p1 = MFMA(Aw[1][4], zf2, p1, 0, 0, 0);                                    \
    q0 = MFMA(Aw[0][5], zf3, q0, 0, 0, 0);                                    \
    q1 = MFMA(Aw[1][5], zf3, q1, 0, 0, 0);                                    \
    const f32x4 a0 = p0 + q0, a1 = p1 + q1;                                   \
    const float x0 = fmaxf(a0[0], 0.f), x1 = fmaxf(a0[1], 0.f);               \
    const float x2 = fmaxf(a0[2], 0.f), x3 = fmaxf(a0[3], 0.f);               \
    const float y0 = fmaxf(a1[0], 0.f), y1 = fmaxf(a1[1], 0.f);               \
    const float y2 = fmaxf(a1[2], 0.f), y3 = fmaxf(a1[3], 0.f);               \
    unsigned u0, u1, u2, u3;                                                  \
    asm("v_cvt_pk_bf16_f32 %0, %1, %2" : "=v"(u0) : "v"(x0), "v"(x1));        \
    asm("v_cvt_pk_bf16_f32 %0, %1, %2" : "=v"(u1) : "v"(x2), "v"(x3));        \
    asm("v_cvt_pk_bf16_f32 %0, %1, %2" : "=v"(u2) : "v"(y0), "v"(y1));        \
    asm("v_cvt_pk_bf16_f32 %0, %1, %2" : "=v"(u3) : "v"(y2), "v"(y3));        \
    union { unsigned u[4]; bf16x8 v; } zc;                                    \
    zc.u[0] = u0; zc.u[1] = u1; zc.u[2] = u2; zc.u[3] = u3;                   \
    zown = zc.v;                                                              \
    *(bf16x8*)(WR) = zown;                                                    \
    asm volatile("s_waitcnt lgkmcnt(0)" ::: "memory");                        \
    __builtin_amdgcn_s_barrier();                                             \
    asm volatile("" ::: "memory");                                            \
  }

#pragma unroll 1
  for (int t = 0; t < Ln; t += 4) {
    PHASE(0, rA1, rA2, rA3, wB)   // t even: read buf0, write buf1
    PHASE(1, rB1, rB2, rB3, wA)
    PHASE(2, rA1, rA2, rA3, wB)
    PHASE(3, rB1, rB2, rB3, wA)
  }
#undef PHASE
#undef SEQ_PF

  // epilogue: h(1024): own tile in zown, foreign tiles in buf0. Wave w -> vocab tile w.
  {
    const bf16x8 zf1 = *(const bf16x8*)(rA1);
    const bf16x8 zf2 = *(const bf16x8*)(rA2);
    const bf16x8 zf3 = *(const bf16x8*)(rA3);
    const unsigned short* wrow = woutp + (size_t)(16 * w + l15) * En + lg * 8;
    f32x4 o = *(const f32x4*)(b_out + 16 * w + 4 * lg);
    o = MFMA(*(const bf16x8*)(wrow + 32 * w), zown, o, 0, 0, 0);
    o = MFMA(*(const bf16x8*)(wrow + 32 * ((w + 1) & 3)), zf1, o, 0, 0, 0);
    o = MFMA(*(const bf16x8*)(wrow + 32 * ((w + 2) & 3)), zf2, o, 0, 0, 0);
    o = MFMA(*(const bf16x8*)(wrow + 32 * ((w + 3) & 3)), zf3, o, 0, 0, 0);
    *(f32x4*)&out[(size_t)(r0 + l15) * Vn + 16 * w + 4 * lg] = o;
  }
}

// ---------------- fp32 fallback (no workspace needed) ----------------

__global__ __launch_bounds__(256, 1) void rnn_mfma(
    const float* __restrict__ seq, const float* __restrict__ W_in,
    const float* __restrict__ b_in, const float* __restrict__ W_h,
    const float* __restrict__ b_h, const float* __restrict__ W_out,
    const float* __restrict__ b_out, float* __restrict__ out) {
  __shared__ __align__(16) unsigned short hb[2][16][136];

  const int tid = threadIdx.x;
  const int w   = tid >> 6;
  const int l   = tid & 63;
  const int l15 = l & 15;
  const int lg  = l >> 4;
  const int r0  = blockIdx.x * 16;

  bf16x8 Bw[2][6];
  float bcl[2];
#pragma unroll
  for (int n = 0; n < 2; ++n) {
    const int j = 32 * w + 16 * n + l15;
    const float* whr = W_h + j * (2 * En);
    float b = b_h[j];
    for (int e = 0; e < En; ++e) b = fmaf(b_in[e], whr[e], b);
    bcl[n] = b;
#pragma unroll
    for (int kt = 0; kt < 6; ++kt) {
      float v[8];
#pragma unroll
      for (int i = 0; i < 8; ++i) {
        const int k = kt * 32 + lg * 8 + i;
        if (k < Vn) {
          float s = 0.f;
          for (int e = 0; e < En; ++e) s = fmaf(W_in[e * Vn + k], whr[e], s);
          v[i] = s;
        } else {
          v[i] = whr[Vn + k];
        }
      }
      Bw[n][kt] = pack8(v);
    }
  }

  for (int i = tid; i < 2 * 16 * 136; i += 256) ((unsigned short*)hb)[i] = 0;

  const float* sq = seq + ((size_t)(r0 + l15) * Ln) * Vn + lg * 8;
  f32x4 sbuf[4][4];

#define SEQ_PF(BI, T)                                                 \
  { const int tp = ((T) < Ln) ? (T) : (Ln - 1);                       \
    const f32x4* p0 = (const f32x4*)(sq + (size_t)tp * Vn);           \
    const f32x4* p1 = (const f32x4*)(sq + (size_t)tp * Vn + 32);      \
    sbuf[BI][0] = p0[0]; sbuf[BI][1] = p0[1];                         \
    sbuf[BI][2] = p1[0]; sbuf[BI][3] = p1[1]; }

  SEQ_PF(0, 0)
  SEQ_PF(1, 1)
  SEQ_PF(2, 2)
  __syncthreads();

#define PHASE(P)                                                              \
  {                                                                           \
    const int cb = (P) & 1, nb = cb ^ 1;                                      \
    const bf16x8 h0 = *(const bf16x8*)&hb[cb][l15][lg * 8];                   \
    const bf16x8 h1 = *(const bf16x8*)&hb[cb][l15][32 + lg * 8];              \
    const bf16x8 h2 = *(const bf16x8*)&hb[cb][l15][64 + lg * 8];              \
    const bf16x8 h3 = *(const bf16x8*)&hb[cb][l15][96 + lg * 8];              \
    SEQ_PF(((P) + 3) & 3, t + (P) + 3);                                       \
    float v0[8], v1[8];                                                       \
    _Pragma("unroll") for (int i = 0; i < 4; ++i) {                           \
      v0[i] = sbuf[(P)][0][i]; v0[4 + i] = sbuf[(P)][1][i];                   \
      v1[i] = sbuf[(P)][2][i]; v1[4 + i] = sbuf[(P)][3][i];                   \
    }                                                                         \
    const bf16x8 a0 = pack8(v0), a1 = pack8(v1);                              \
    f32x4 p0a = {bcl[0], bcl[0], bcl[0], bcl[0]};                             \
    f32x4 p1a = {bcl[1], bcl[1], bcl[1], bcl[1]};                             \
    f32x4 q0a = {0.f, 0.f, 0.f, 0.f}, q1a = {0.f, 0.f, 0.f, 0.f};             \
    p0a = MFMA(a0, Bw[0][0], p0a, 0, 0, 0);                                   \
    p1a = MFMA(a0, Bw[1][0], p1a, 0, 0, 0);                                   \
    p0a = MFMA(a1, Bw[0][1], p0a, 0, 0, 0);                                   \
    p1a = MFMA(a1, Bw[1][1], p1a, 0, 0, 0);                                   \
    p0a = MFMA(h0, Bw[0][2], p0a, 0, 0, 0);                                   \
    p1a = MFMA(h0, Bw[1][2], p1a, 0, 0, 0);                                   \
    q0a = MFMA(h2, Bw[0][4], q0a, 0, 0, 0);                                   \
    q1a = MFMA(h2, Bw[1][4], q1a, 0, 0, 0);                                   \
    p0a = MFMA(h1, Bw[0][3], p0a, 0, 0, 0);                                   \
    p1a = MFMA(h1, Bw[1][3], p1a, 0, 0, 0);                                   \
    q0a = MFMA(h3, Bw[0][5], q0a, 0, 0, 0);                                   \
    q1a = MFMA(h3, Bw[1][5], q1a, 0, 0, 0);                                   \
    const int j0 = 32 * w + l15, j1 = j0 + 16, rr = 4 * lg;                   \
    _Pragma("unroll") for (int i = 0; i < 4; ++i) {                           \
      hb[nb][rr + i][j0] = (unsigned short)f2b(fmaxf(p0a[i] + q0a[i], 0.f));  \
      hb[nb][rr + i][j1] = (unsigned short)f2b(fmaxf(p1a[i] + q1a[i], 0.f));  \
    }                                                                         \
    asm volatile("s_waitcnt lgkmcnt(0)" ::: "memory");                        \
    __builtin_amdgcn_s_barrier();                                             \
    asm volatile("" ::: "memory");                                            \
  }

#pragma unroll 1
  for (int t = 0; t < Ln; t += 4) {
    PHASE(0)
    PHASE(1)
    PHASE(2)
    PHASE(3)
  }
#undef PHASE
#undef SEQ_PF

  const int orow = tid >> 4;
  const int oc   = (tid & 15) * 4;
  float o0 = b_out[oc], o1 = b_out[oc + 1], o2 = b_out[oc + 2], o3 = b_out[oc + 3];
  const float* w0 = W_out + (size_t)(oc + 0) * En;
  const float* w1 = W_out + (size_t)(oc + 1) * En;
  const float* w2 = W_out + (size_t)(oc + 2) * En;
  const float* w3 = W_out + (size_t)(oc + 3) * En;
#pragma unroll 8
  for (int k = 0; k < En; ++k) {
    const float hv = b2f(hb[0][orow][k]);
    o0 = fmaf(hv, w0[k], o0);
    o1 = fmaf(hv, w1[k], o1);
    o2 = fmaf(hv, w2[k], o2);
    o3 = fmaf(hv, w3[k], o3);
  }
  *(float4*)&out[(size_t)(r0 + orow) * Vn + oc] = make_float4(o0, o1, o2, o3);
}

extern "C" void kernel_launch(void* const* d_in, const int* in_sizes, int n_in,
                              void* d_out, int out_size, void* d_ws, size_t ws_size,
                              hipStream_t stream) {
  const float* seq   = (const float*)d_in[0];
  const float* W_in  = (const float*)d_in[1];
  const float* b_in  = (const float*)d_in[2];
  const float* W_h   = (const float*)d_in[3];
  const float* b_h   = (const float*)d_in[4];
  const float* W_out = (const float*)d_in[5];
  const float* b_out = (const float*)d_in[6];
  float* out = (float*)d_out;

  if (ws_size >= SMALL_WS) {
    unsigned short* wall2 = (unsigned short*)d_ws;
    float* bc             = (float*)((char*)d_ws + WALLB_BYTES);
    unsigned short* woutp = (unsigned short*)((char*)d_ws + WALLB_BYTES + BC_BYTES);
    rnn_setup_all<<<192, 192, 0, stream>>>(W_in, b_in, W_h, b_h, W_out, wall2, bc, woutp);
    rnn_quad_f32<<<Bn / 16, 256, 0, stream>>>(seq, wall2, bc, woutp, b_out, out);
  } else {
    rnn_mfma<<<Bn / 16, 256, 0, stream>>>(seq, W_in, b_in, W_h, b_h, W_out, b_out, out);
  }
}

// Round 17
// 280.072 us; speedup vs baseline: 1.7276x; 1.7276x over previous
//
#include <hip/hip_runtime.h>
#include <hip/hip_bf16.h>

namespace {
constexpr int Bn = 512;
constexpr int Ln = 1024;
constexpr int Vn = 64;
constexpr int En = 128;
constexpr int Kc = Vn + En;              // 192
constexpr size_t SEQB_BYTES  = (size_t)Bn * Ln * Vn * 2;  // 67,108,864
constexpr size_t WALLB_BYTES = (size_t)En * Kc * 2;       // 49,152
constexpr size_t BC_BYTES    = En * 4;                    // 512
constexpr size_t WOUTP_BYTES = (size_t)Vn * En * 2;       // 16,384
constexpr size_t FAST_WS2 = SEQB_BYTES + WALLB_BYTES + BC_BYTES + WOUTP_BYTES;
}

typedef __attribute__((ext_vector_type(8))) short bf16x8;
typedef __attribute__((ext_vector_type(4))) float f32x4;
typedef __attribute__((ext_vector_type(8))) unsigned short u16x8;

__device__ __forceinline__ unsigned f2b(float f) {
  unsigned u = __float_as_uint(f);
  u += 0x7fffu + ((u >> 16) & 1u);
  return u >> 16;
}
__device__ __forceinline__ float b2f(unsigned short b) {
  return __uint_as_float(((unsigned)b) << 16);
}
__device__ __forceinline__ bf16x8 pack8(const float* v) {
  bf16x8 r;
#pragma unroll
  for (int i = 0; i < 8; ++i) r[i] = (short)f2b(v[i]);
  return r;
}

// column permutation for the h cycle (16x16x32, 4-wave):
// k-tile tau, frag elem e at k-group lg:  kk = 32*tau + 8*lg + e
// -> h col m(kk) = 32*tau + 16*(e>>2) + 4*lg + (e&3)
__device__ __forceinline__ int cm4(int kk) {
  return 32 * (kk >> 5) + 16 * ((kk >> 2) & 1) + 4 * ((kk >> 3) & 3) + (kk & 3);
}

#define MFMA __builtin_amdgcn_mfma_f32_16x16x32_bf16

// ---------------- seq fp32 -> bf16 prepass (memory-bound, ~30us) ----------------
__global__ void seq_cvt(const float* __restrict__ seq, unsigned short* __restrict__ seqb) {
  const size_t n = (size_t)Bn * Ln * Vn;
  size_t i = ((size_t)blockIdx.x * blockDim.x + threadIdx.x) * 8;
  const size_t stride = (size_t)gridDim.x * blockDim.x * 8;
  for (; i < n; i += stride) {
    const f32x4 a = *(const f32x4*)(seq + i);
    const f32x4 b = *(const f32x4*)(seq + i + 4);
    u16x8 o;
#pragma unroll
    for (int j = 0; j < 4; ++j) o[j] = (unsigned short)f2b(a[j]);
#pragma unroll
    for (int j = 0; j < 4; ++j) o[4 + j] = (unsigned short)f2b(b[j]);
    *(u16x8*)(seqb + i) = o;
  }
}

// ---------------- merged setup: wall2 + bc (blocks 0..127), woutp (128..191) ----
// wall2[j][k] bf16: k<64 -> folded input proj; k>=64 -> Whh[j][cm4(k-64)]
// bc[j] = b_h[j] + sum_e b_in[e]*W_h[j][e];  woutp[v][kk] = W_out[v][cm4(kk)]
__global__ __launch_bounds__(192) void rnn_setup_all(
    const float* __restrict__ W_in, const float* __restrict__ b_in,
    const float* __restrict__ W_h, const float* __restrict__ b_h,
    const float* __restrict__ W_out, unsigned short* __restrict__ wall2,
    float* __restrict__ bc, unsigned short* __restrict__ woutp) {
  const int tid = threadIdx.x;
  if (blockIdx.x < 128) {
    const int j = blockIdx.x;
    const int k = tid;  // 0..191
    const float* whr = W_h + j * (2 * En);
    float s;
    if (k < Vn) {
      s = 0.f;
#pragma unroll 8
      for (int e = 0; e < En; ++e) s = fmaf(W_in[e * Vn + k], whr[e], s);
    } else {
      s = whr[En + cm4(k - Vn)];
    }
    wall2[j * Kc + k] = (unsigned short)f2b(s);
    if (k == 0) {
      float b = b_h[j];
      for (int e = 0; e < En; ++e) b = fmaf(b_in[e], whr[e], b);
      bc[j] = b;
    }
  } else {
    const int v = blockIdx.x - 128;  // 0..63
    if (tid < En)
      woutp[v * En + tid] = (unsigned short)f2b(W_out[(size_t)v * En + cm4(tid)]);
  }
}

// ---------------- main kernel (r13 champion): 4 waves, 12 MFMA/wave ----------
// Wave w owns n-tiles {2w,2w+1} = h cols [32w,32w+32) = z k-tile w; under cm4
// its packed relu output IS its own 16B B-frag (zown, register-resident).
// 3 foreign tiles via lane-linear conflict-free LDS (tile=1024B, lane l at
// byte l*16). Per step: 12 MFMA (4 seq + 8 z), 3 ds_read_b128 + 1
// ds_write_b128, 1 lgkm-drain + barrier. Measured floor ~566 cyc/step —
// insensitive to MFMA count (r15), MFMA width (r14), wave count (r7/r8/r12),
// bank conflicts (r10): the barrier->read->MFMA->pack->write->drain chain IS
// the serial recurrence's latency-critical path.
__global__ __launch_bounds__(256, 1) void rnn_quad(
    const unsigned short* __restrict__ seqb, const unsigned short* __restrict__ wall2,
    const float* __restrict__ bc, const unsigned short* __restrict__ woutp,
    const float* __restrict__ b_out, float* __restrict__ out) {
  __shared__ __align__(16) unsigned char zlds[2][4][1024];  // [buf][tile][lane16B]

  const int tid = threadIdx.x;
  const int w   = tid >> 6;        // wave 0..3 = owned k-tile
  const int l   = tid & 63;
  const int l15 = l & 15;          // batch col / A row
  const int lg  = l >> 4;          // k-group / C row-group
  const int r0  = blockIdx.x * 16;

  // weights for n-tiles 2w (Aw[0]) and 2w+1 (Aw[1]); [kt]: 0,1=seq, 2+p=z tile (w+p)&3
  bf16x8 Aw[2][6];
#pragma unroll
  for (int nn = 0; nn < 2; ++nn) {
    const unsigned short* row = wall2 + (size_t)(16 * (2 * w + nn) + l15) * Kc + lg * 8;
    Aw[nn][0] = *(const bf16x8*)(row);
    Aw[nn][1] = *(const bf16x8*)(row + 32);
#pragma unroll
    for (int p = 0; p < 4; ++p)
      Aw[nn][2 + p] = *(const bf16x8*)(row + Vn + 32 * ((w + p) & 3));
  }
  const f32x4 bcv0 = *(const f32x4*)(bc + 32 * w + 4 * lg);
  const f32x4 bcv1 = *(const f32x4*)(bc + 32 * w + 16 + 4 * lg);

  const int ro  = l * 16;  // lane slot within a tile (stride-1, conflict-free)
  const unsigned char* rA1 = &zlds[0][(w + 1) & 3][ro];
  const unsigned char* rA2 = &zlds[0][(w + 2) & 3][ro];
  const unsigned char* rA3 = &zlds[0][(w + 3) & 3][ro];
  const unsigned char* rB1 = &zlds[1][(w + 1) & 3][ro];
  const unsigned char* rB2 = &zlds[1][(w + 2) & 3][ro];
  const unsigned char* rB3 = &zlds[1][(w + 3) & 3][ro];
  unsigned char* wA = &zlds[0][w][ro];
  unsigned char* wB = &zlds[1][w][ro];

  // h(0) = 0
  for (int i = tid; i < 2048; i += 256) ((unsigned int*)zlds)[i] = 0u;
  bf16x8 zown;
#pragma unroll
  for (int i = 0; i < 8; ++i) zown[i] = 0;

  const unsigned short* sqb = seqb + ((size_t)(r0 + l15) * Ln) * Vn + lg * 8;
  bf16x8 sreg[4][2];

#define SEQ_PF(BI, T)                                                \
  { const int tp = ((T) < Ln) ? (T) : (Ln - 1);                      \
    const bf16x8* sp = (const bf16x8*)(sqb + (size_t)tp * Vn);       \
    sreg[BI][0] = sp[0];                                             \
    sreg[BI][1] = sp[4]; }

  SEQ_PF(0, 0)
  SEQ_PF(1, 1)
  SEQ_PF(2, 2)
  __syncthreads();

#define PHASE(P, R1, R2, R3, WR)                                              \
  {                                                                           \
    const bf16x8 zf1 = *(const bf16x8*)(R1);                                  \
    const bf16x8 zf2 = *(const bf16x8*)(R2);                                  \
    const bf16x8 zf3 = *(const bf16x8*)(R3);                                  \
    SEQ_PF(((P) + 3) & 3, t + (P) + 3);                                       \
    const bf16x8 s0 = sreg[(P)][0], s1 = sreg[(P)][1];                        \
    f32x4 p0 = MFMA(Aw[0][0], s0, bcv0, 0, 0, 0);                             \
    f32x4 p1 = MFMA(Aw[1][0], s0, bcv1, 0, 0, 0);                             \
    f32x4 q0 = {0.f, 0.f, 0.f, 0.f}, q1 = {0.f, 0.f, 0.f, 0.f};               \
    q0 = MFMA(Aw[0][1], s1, q0, 0, 0, 0);                                     \
    q1 = MFMA(Aw[1][1], s1, q1, 0, 0, 0);                                     \
    p0 = MFMA(Aw[0][2], zown, p0, 0, 0, 0);                                   \
    p1 = MFMA(Aw[1][2], zown, p1, 0, 0, 0);                                   \
    q0 = MFMA(Aw[0][3], zf1, q0, 0, 0, 0);                                    \
    q1 = MFMA(Aw[1][3], zf1, q1, 0, 0, 0);                                    \
    p0 = MFMA(Aw[0][4], zf2, p0, 0, 0, 0);                                    \
    p1 = MFMA(Aw[1][4], zf2, p1, 0, 0, 0);                                    \
    q0 = MFMA(Aw[0][5], zf3, q0, 0, 0, 0);                                    \
    q1 = MFMA(Aw[1][5], zf3, q1, 0, 0, 0);                                    \
    const f32x4 a0 = p0 + q0, a1 = p1 + q1;                                   \
    const float x0 = fmaxf(a0[0], 0.f), x1 = fmaxf(a0[1], 0.f);               \
    const float x2 = fmaxf(a0[2], 0.f), x3 = fmaxf(a0[3], 0.f);               \
    const float y0 = fmaxf(a1[0], 0.f), y1 = fmaxf(a1[1], 0.f);               \
    const float y2 = fmaxf(a1[2], 0.f), y3 = fmaxf(a1[3], 0.f);               \
    unsigned u0, u1, u2, u3;                                                  \
    asm("v_cvt_pk_bf16_f32 %0, %1, %2" : "=v"(u0) : "v"(x0), "v"(x1));        \
    asm("v_cvt_pk_bf16_f32 %0, %1, %2" : "=v"(u1) : "v"(x2), "v"(x3));        \
    asm("v_cvt_pk_bf16_f32 %0, %1, %2" : "=v"(u2) : "v"(y0), "v"(y1));        \
    asm("v_cvt_pk_bf16_f32 %0, %1, %2" : "=v"(u3) : "v"(y2), "v"(y3));        \
    union { unsigned u[4]; bf16x8 v; } zc;                                    \
    zc.u[0] = u0; zc.u[1] = u1; zc.u[2] = u2; zc.u[3] = u3;                   \
    zown = zc.v;                                                              \
    *(bf16x8*)(WR) = zown;                                                    \
    asm volatile("s_waitcnt lgkmcnt(0)" ::: "memory");                        \
    __builtin_amdgcn_s_barrier();                                             \
    asm volatile("" ::: "memory");                                            \
  }

#pragma unroll 1
  for (int t = 0; t < Ln; t += 4) {
    PHASE(0, rA1, rA2, rA3, wB)   // t even: read buf0, write buf1
    PHASE(1, rB1, rB2, rB3, wA)
    PHASE(2, rA1, rA2, rA3, wB)
    PHASE(3, rB1, rB2, rB3, wA)
  }
#undef PHASE
#undef SEQ_PF

  // epilogue: h(1024): own tile in zown, foreign tiles in buf0. Wave w -> vocab tile w.
  {
    const bf16x8 zf1 = *(const bf16x8*)(rA1);
    const bf16x8 zf2 = *(const bf16x8*)(rA2);
    const bf16x8 zf3 = *(const bf16x8*)(rA3);
    const unsigned short* wrow = woutp + (size_t)(16 * w + l15) * En + lg * 8;
    f32x4 o = *(const f32x4*)(b_out + 16 * w + 4 * lg);
    o = MFMA(*(const bf16x8*)(wrow + 32 * w), zown, o, 0, 0, 0);
    o = MFMA(*(const bf16x8*)(wrow + 32 * ((w + 1) & 3)), zf1, o, 0, 0, 0);
    o = MFMA(*(const bf16x8*)(wrow + 32 * ((w + 2) & 3)), zf2, o, 0, 0, 0);
    o = MFMA(*(const bf16x8*)(wrow + 32 * ((w + 3) & 3)), zf3, o, 0, 0, 0);
    *(f32x4*)&out[(size_t)(r0 + l15) * Vn + 16 * w + 4 * lg] = o;
  }
}

// ---------------- fp32 fallback (no workspace needed) ----------------

__global__ __launch_bounds__(256, 1) void rnn_mfma(
    const float* __restrict__ seq, const float* __restrict__ W_in,
    const float* __restrict__ b_in, const float* __restrict__ W_h,
    const float* __restrict__ b_h, const float* __restrict__ W_out,
    const float* __restrict__ b_out, float* __restrict__ out) {
  __shared__ __align__(16) unsigned short hb[2][16][136];

  const int tid = threadIdx.x;
  const int w   = tid >> 6;
  const int l   = tid & 63;
  const int l15 = l & 15;
  const int lg  = l >> 4;
  const int r0  = blockIdx.x * 16;

  bf16x8 Bw[2][6];
  float bcl[2];
#pragma unroll
  for (int n = 0; n < 2; ++n) {
    const int j = 32 * w + 16 * n + l15;
    const float* whr = W_h + j * (2 * En);
    float b = b_h[j];
    for (int e = 0; e < En; ++e) b = fmaf(b_in[e], whr[e], b);
    bcl[n] = b;
#pragma unroll
    for (int kt = 0; kt < 6; ++kt) {
      float v[8];
#pragma unroll
      for (int i = 0; i < 8; ++i) {
        const int k = kt * 32 + lg * 8 + i;
        if (k < Vn) {
          float s = 0.f;
          for (int e = 0; e < En; ++e) s = fmaf(W_in[e * Vn + k], whr[e], s);
          v[i] = s;
        } else {
          v[i] = whr[Vn + k];
        }
      }
      Bw[n][kt] = pack8(v);
    }
  }

  for (int i = tid; i < 2 * 16 * 136; i += 256) ((unsigned short*)hb)[i] = 0;

  const float* sq = seq + ((size_t)(r0 + l15) * Ln) * Vn + lg * 8;
  f32x4 sbuf[4][4];

#define SEQ_PF(BI, T)                                                 \
  { const int tp = ((T) < Ln) ? (T) : (Ln - 1);                       \
    const f32x4* p0 = (const f32x4*)(sq + (size_t)tp * Vn);           \
    const f32x4* p1 = (const f32x4*)(sq + (size_t)tp * Vn + 32);      \
    sbuf[BI][0] = p0[0]; sbuf[BI][1] = p0[1];                         \
    sbuf[BI][2] = p1[0]; sbuf[BI][3] = p1[1]; }

  SEQ_PF(0, 0)
  SEQ_PF(1, 1)
  SEQ_PF(2, 2)
  __syncthreads();

#define PHASE(P)                                                              \
  {                                                                           \
    const int cb = (P) & 1, nb = cb ^ 1;                                      \
    const bf16x8 h0 = *(const bf16x8*)&hb[cb][l15][lg * 8];                   \
    const bf16x8 h1 = *(const bf16x8*)&hb[cb][l15][32 + lg * 8];              \
    const bf16x8 h2 = *(const bf16x8*)&hb[cb][l15][64 + lg * 8];              \
    const bf16x8 h3 = *(const bf16x8*)&hb[cb][l15][96 + lg * 8];              \
    SEQ_PF(((P) + 3) & 3, t + (P) + 3);                                       \
    float v0[8], v1[8];                                                       \
    _Pragma("unroll") for (int i = 0; i < 4; ++i) {                           \
      v0[i] = sbuf[(P)][0][i]; v0[4 + i] = sbuf[(P)][1][i];                   \
      v1[i] = sbuf[(P)][2][i]; v1[4 + i] = sbuf[(P)][3][i];                   \
    }                                                                         \
    const bf16x8 a0 = pack8(v0), a1 = pack8(v1);                              \
    f32x4 p0a = {bcl[0], bcl[0], bcl[0], bcl[0]};                             \
    f32x4 p1a = {bcl[1], bcl[1], bcl[1], bcl[1]};                             \
    f32x4 q0a = {0.f, 0.f, 0.f, 0.f}, q1a = {0.f, 0.f, 0.f, 0.f};             \
    p0a = MFMA(a0, Bw[0][0], p0a, 0, 0, 0);                                   \
    p1a = MFMA(a0, Bw[1][0], p1a, 0, 0, 0);                                   \
    p0a = MFMA(a1, Bw[0][1], p0a, 0, 0, 0);                                   \
    p1a = MFMA(a1, Bw[1][1], p1a, 0, 0, 0);                                   \
    p0a = MFMA(h0, Bw[0][2], p0a, 0, 0, 0);                                   \
    p1a = MFMA(h0, Bw[1][2], p1a, 0, 0, 0);                                   \
    q0a = MFMA(h2, Bw[0][4], q0a, 0, 0, 0);                                   \
    q1a = MFMA(h2, Bw[1][4], q1a, 0, 0, 0);                                   \
    p0a = MFMA(h1, Bw[0][3], p0a, 0, 0, 0);                                   \
    p1a = MFMA(h1, Bw[1][3], p1a, 0, 0, 0);                                   \
    q0a = MFMA(h3, Bw[0][5], q0a, 0, 0, 0);                                   \
    q1a = MFMA(h3, Bw[1][5], q1a, 0, 0, 0);                                   \
    const int j0 = 32 * w + l15, j1 = j0 + 16, rr = 4 * lg;                   \
    _Pragma("unroll") for (int i = 0; i < 4; ++i) {                           \
      hb[nb][rr + i][j0] = (unsigned short)f2b(fmaxf(p0a[i] + q0a[i], 0.f));  \
      hb[nb][rr + i][j1] = (unsigned short)f2b(fmaxf(p1a[i] + q1a[i], 0.f));  \
    }                                                                         \
    asm volatile("s_waitcnt lgkmcnt(0)" ::: "memory");                        \
    __builtin_amdgcn_s_barrier();                                             \
    asm volatile("" ::: "memory");                                            \
  }

#pragma unroll 1
  for (int t = 0; t < Ln; t += 4) {
    PHASE(0)
    PHASE(1)
    PHASE(2)
    PHASE(3)
  }
#undef PHASE
#undef SEQ_PF

  const int orow = tid >> 4;
  const int oc   = (tid & 15) * 4;
  float o0 = b_out[oc], o1 = b_out[oc + 1], o2 = b_out[oc + 2], o3 = b_out[oc + 3];
  const float* w0 = W_out + (size_t)(oc + 0) * En;
  const float* w1 = W_out + (size_t)(oc + 1) * En;
  const float* w2 = W_out + (size_t)(oc + 2) * En;
  const float* w3 = W_out + (size_t)(oc + 3) * En;
#pragma unroll 8
  for (int k = 0; k < En; ++k) {
    const float hv = b2f(hb[0][orow][k]);
    o0 = fmaf(hv, w0[k], o0);
    o1 = fmaf(hv, w1[k], o1);
    o2 = fmaf(hv, w2[k], o2);
    o3 = fmaf(hv, w3[k], o3);
  }
  *(float4*)&out[(size_t)(r0 + orow) * Vn + oc] = make_float4(o0, o1, o2, o3);
}

extern "C" void kernel_launch(void* const* d_in, const int* in_sizes, int n_in,
                              void* d_out, int out_size, void* d_ws, size_t ws_size,
                              hipStream_t stream) {
  const float* seq   = (const float*)d_in[0];
  const float* W_in  = (const float*)d_in[1];
  const float* b_in  = (const float*)d_in[2];
  const float* W_h   = (const float*)d_in[3];
  const float* b_h   = (const float*)d_in[4];
  const float* W_out = (const float*)d_in[5];
  const float* b_out = (const float*)d_in[6];
  float* out = (float*)d_out;

  if (ws_size >= FAST_WS2) {
    unsigned short* seqb  = (unsigned short*)d_ws;
    unsigned short* wall2 = (unsigned short*)((char*)d_ws + SEQB_BYTES);
    float* bc             = (float*)((char*)d_ws + SEQB_BYTES + WALLB_BYTES);
    unsigned short* woutp = (unsigned short*)((char*)d_ws + SEQB_BYTES + WALLB_BYTES + BC_BYTES);
    seq_cvt<<<2048, 256, 0, stream>>>(seq, seqb);
    rnn_setup_all<<<192, 192, 0, stream>>>(W_in, b_in, W_h, b_h, W_out, wall2, bc, woutp);
    rnn_quad<<<Bn / 16, 256, 0, stream>>>(seqb, wall2, bc, woutp, b_out, out);
  } else {
    rnn_mfma<<<Bn / 16, 256, 0, stream>>>(seq, W_in, b_in, W_h, b_h, W_out, b_out, out);
  }
}